// Round 1
// baseline (1125.369 us; speedup 1.0000x reference)
//
#include <hip/hip_runtime.h>
#include <hip/hip_bf16.h>

// MeshConv: g = [x0, x1+x3, x2+x4, |x1-x3|, |x2-x4|] stacked as H=5,
// then NCHW conv with OIHW W of shape (16,16,1,5), VALID -> out (4,16,5,F-4), + bias.
//
// Layout facts:
//   x[n,i,f,k]  = x[((n*16+i)*F + f)*5 + k]        (K=5 innermost, contiguous)
//   W[o,i,0,kw] = W[(o*16+i)*5 + kw]
//   y[n,o,h,w]  = y[((n*16+o)*5 + h)*(F-4) + w]
//   y[n,o,h,w]  = b[o] + sum_i sum_kw W[o,i,kw] * g[n,i,h,w+kw]
//
// Strategy: block = 256 thr, tile TF=64 output positions per (block, n).
// Stage g for 16 channels x 68 positions x 5 rows in LDS (21.76 KB),
// stride-5-dword layout (5 coprime 32 -> conflict-free).
// Thread (wl = t&63, og = t>>6) computes w = w0+wl for o in [4*og, 4*og+4), all 5 h.
// W indices wave-uniform (og via readfirstlane) -> scalar loads.

constexpr int NN   = 4;
constexpr int CIN  = 16;
constexpr int COUT = 16;
constexpr int FF   = 500000;
constexpr int KK   = 5;
constexpr int FO   = FF - 4;     // 499996
constexpr int TF   = 64;         // output positions per block
constexpr int TFH  = TF + 4;     // staged positions (halo)

__global__ __launch_bounds__(256, 2)
void meshconv_kernel(const float* __restrict__ x,
                     const float* __restrict__ W,
                     const float* __restrict__ b,
                     float* __restrict__ out)
{
    __shared__ float g_lds[CIN * TFH * 5];   // [i][fl][h], 21760 B

    const int n  = blockIdx.y;
    const int w0 = blockIdx.x * TF;
    const int t  = threadIdx.x;

    // ---- Stage: load x, build g rows, write LDS ----
    // 16*68 = 1088 (i, fl) pairs; each pair = 5 contiguous x floats -> 5 g floats.
    for (int p = t; p < CIN * TFH; p += 256) {
        const int i  = p / TFH;
        const int fl = p - i * TFH;
        const int f  = w0 + fl;
        float x0 = 0.f, x1 = 0.f, x2 = 0.f, x3 = 0.f, x4 = 0.f;
        if (f < FF) {
            const float* xp = x + ((n * CIN + i) * (size_t)FF + f) * KK;
            x0 = xp[0]; x1 = xp[1]; x2 = xp[2]; x3 = xp[3]; x4 = xp[4];
        }
        float* gp = g_lds + p * 5;
        gp[0] = x0;
        gp[1] = x1 + x3;
        gp[2] = x2 + x4;
        gp[3] = fabsf(x1 - x3);
        gp[4] = fabsf(x2 - x4);
    }
    __syncthreads();

    // ---- Compute ----
    const int wl = t & 63;
    const int og = __builtin_amdgcn_readfirstlane(t >> 6);   // wave-uniform o-group
    const int w  = w0 + wl;

    float acc[5][4];
    #pragma unroll
    for (int h = 0; h < 5; ++h)
        #pragma unroll
        for (int oo = 0; oo < 4; ++oo) acc[h][oo] = 0.f;

    for (int i = 0; i < CIN; ++i) {
        // W slice for this (og, i): 4 o x 5 kw, wave-uniform -> SGPRs
        float ws[4][5];
        #pragma unroll
        for (int oo = 0; oo < 4; ++oo)
            #pragma unroll
            for (int kw = 0; kw < KK; ++kw)
                ws[oo][kw] = W[((og * 4 + oo) * CIN + i) * KK + kw];

        const float* gi = g_lds + (i * TFH + wl) * 5;
        #pragma unroll
        for (int kw = 0; kw < KK; ++kw) {
            float gh[5];
            #pragma unroll
            for (int h = 0; h < 5; ++h) gh[h] = gi[kw * 5 + h];
            #pragma unroll
            for (int oo = 0; oo < 4; ++oo)
                #pragma unroll
                for (int h = 0; h < 5; ++h)
                    acc[h][oo] = fmaf(ws[oo][kw], gh[h], acc[h][oo]);
        }
    }

    // ---- Epilogue: bias + store ----
    if (w < FO) {
        #pragma unroll
        for (int oo = 0; oo < 4; ++oo) {
            const int o = og * 4 + oo;
            const float bias = b[o];
            #pragma unroll
            for (int h = 0; h < 5; ++h)
                out[((n * COUT + o) * 5 + h) * (size_t)FO + w] = acc[h][oo] + bias;
        }
    }
}

extern "C" void kernel_launch(void* const* d_in, const int* in_sizes, int n_in,
                              void* d_out, int out_size, void* d_ws, size_t ws_size,
                              hipStream_t stream)
{
    const float* x = (const float*)d_in[0];
    const float* W = (const float*)d_in[1];
    const float* b = (const float*)d_in[2];
    float* out = (float*)d_out;

    const int ntiles = (FO + TF - 1) / TF;   // 7813
    dim3 grid(ntiles, NN);
    dim3 block(256);
    meshconv_kernel<<<grid, block, 0, stream>>>(x, W, b, out);
}